// Round 9
// baseline (97.952 us; speedup 1.0000x reference)
//
#include <hip/hip_runtime.h>
#include <hip/hip_bf16.h>
#include <math.h>

#define BDIM 4096
#define DDIM 2048
#define PDIM 128
#define CDIM 10
#define TB   8192   // 2*B

// exp(cos/TEMP) with TEMP=0.5  ->  exp2(cos * 2/ln2)
#define EXP_SCALE 2.8853900817779268f
#define LAMBDA 0.2f
#define EPS 1e-8f

typedef __bf16 bfv8 __attribute__((ext_vector_type(8)));
typedef float  fv4  __attribute__((ext_vector_type(4)));

__device__ __forceinline__ unsigned short f2bf(float f) {
    unsigned int u = __float_as_uint(f);
    u += 0x7FFFu + ((u >> 16) & 1u);      // round-to-nearest-even
    return (unsigned short)(u >> 16);
}

// ws layout (float index):
//  [0]                    sup_acc
//  [1]                    flag (int)
//  [16 .. 16+8192)        rowsum
//  [16+8192 .. 16+16384)  possum
//  [16400 ..)             phat  [8192][128] bf16   (524288 floats)
//  [540688 ..)            WpT   [128][2048] bf16   (131072 floats)
//  [671760 ..)            WcT   [16][2048]  bf16   (16384 floats)

// ---------------- k0: zero accumulators (+ out) ----------------
__global__ void k0_zero(float* __restrict__ ws_f, float* __restrict__ out) {
    int idx = blockIdx.x * 256 + threadIdx.x;
    if (idx < 16 + 2 * TB) ws_f[idx] = 0.0f;
    if (idx == 0) out[0] = 0.0f;
}

// ---------------- kf: detect int64 label layout ----------------
__global__ void kf_flag(const int* __restrict__ y32, int* __restrict__ flag_out) {
    __shared__ int s_ok;
    if (threadIdx.x == 0) s_ok = 1;
    __syncthreads();
    int ok = 1;
    #pragma unroll
    for (int i = 0; i < 8; ++i) {
        int w = 2 * (threadIdx.x + 256 * i) + 1;   // odd words 1..4095
        if (y32[w] != 0) ok = 0;
    }
    if (!ok) atomicAnd(&s_ok, 0);
    __syncthreads();
    if (threadIdx.x == 0) *flag_out = s_ok;
}

// ---------------- kw: build bf16 transposed weights ----------------
__global__ __launch_bounds__(256) void kw_prep(
    const float* __restrict__ Wp, const float* __restrict__ Wc,
    unsigned short* __restrict__ WpT, unsigned short* __restrict__ WcT)
{
    int idx = blockIdx.x * 256 + threadIdx.x;
    if (idx < PDIM * DDIM) {
        int p = idx >> 11, k = idx & 2047;
        WpT[idx] = f2bf(Wp[(size_t)k * PDIM + p]);
    } else {
        int j = idx - PDIM * DDIM;          // < 16*2048
        int c = j >> 11, k = j & 2047;
        WcT[j] = (c < CDIM) ? f2bf(Wc[(size_t)k * CDIM + c]) : (unsigned short)0;
    }
}

// ---------------- k13: fused proj-GEMM + normalize + digits + CE -----------
// 512 blocks x 512 thr (8 waves). Block owns 16 rows; K staged in LDS tiles
// of BK=512 (double-buffered bf16) -> only 4 barrier-drains, 4 float4/thread
// in flight per tile. Swizzle: byte col c of row r at c ^ ((r&15)<<4), same
// involution both sides, XOR applied to full column offset.
// Wave w owns proj n-tile w; digits: wave w handles ks2 in {2w,2w+1} per tile.
__global__ __launch_bounds__(512) void k13_fused(
    const float* __restrict__ xi, const float* __restrict__ xj,
    const __bf16* __restrict__ WpT, const __bf16* __restrict__ WcT,
    const int* __restrict__ y, const int* __restrict__ flag_p,
    unsigned short* __restrict__ phat, float* __restrict__ sup_acc)
{
    __shared__ unsigned short Xs[2][16 * 512];  // 32 KB bf16, swizzled
    __shared__ float sproj[16][132];            // 8.25 KB
    __shared__ float sdig[8][16][16];           // 8 KB
    __shared__ float sce[16];

    const int tid = threadIdx.x;
    const int wv = tid >> 6, lane = tid & 63;
    const int l15 = lane & 15, lg = lane >> 4;
    const int R0 = blockIdx.x * 16;
    const float* src = (R0 < BDIM) ? (xi + (size_t)R0 * DDIM)
                                   : (xj + (size_t)(R0 - BDIM) * DDIM);
    // coalesced staging map: row = tid>>5, float-col (t&31)*4 within 128-float round q
    const int xrw = tid >> 5;
    const float* gsrc = src + (size_t)xrw * DDIM + (tid & 31) * 4;
    int wb[4];
    #pragma unroll
    for (int q = 0; q < 4; ++q)
        wb[q] = xrw * 1024 + ((q * 256 + (tid & 31) * 8) ^ ((xrw & 15) << 4));
    // A-fragment read: row l15, col byte (ks2*64 + lg*16) ^ (l15<<4)
    const int arowb = l15 * 1024;
    const int swz   = l15 << 4;

    const __bf16* brow = WpT + (size_t)(wv * 16 + l15) * DDIM + lg * 8;
    const __bf16* crow = WcT + (size_t)l15 * DDIM + lg * 8;

    fv4 acc = {}, accd = {};

    // stage tile 0
    #pragma unroll
    for (int q = 0; q < 4; ++q) {
        float4 f = *(const float4*)(gsrc + q * 128);
        ushort4 w;
        w.x = f2bf(f.x); w.y = f2bf(f.y); w.z = f2bf(f.z); w.w = f2bf(f.w);
        *(ushort4*)((char*)&Xs[0][0] + wb[q]) = w;
    }

    for (int kt = 0; kt < 4; ++kt) {
        __syncthreads();
        // issue next-tile loads right after the barrier (in flight over compute)
        float4 nf[4];
        if (kt < 3) {
            #pragma unroll
            for (int q = 0; q < 4; ++q)
                nf[q] = *(const float4*)(gsrc + (size_t)(kt + 1) * 512 + q * 128);
        }

        const char* xb = (const char*)&Xs[kt & 1][0];
        #pragma unroll
        for (int ks2 = 0; ks2 < 16; ++ks2) {
            bfv8 a = *(const bfv8*)(xb + arowb + ((ks2 * 64 + lg * 16) ^ swz));
            bfv8 b = *(const bfv8*)(brow + (size_t)kt * 512 + ks2 * 32);
            acc = __builtin_amdgcn_mfma_f32_16x16x32_bf16(a, b, acc, 0, 0, 0);
            if ((ks2 >> 1) == wv) {   // wave-uniform: wave w owns slices 2w,2w+1
                bfv8 bc = *(const bfv8*)(crow + (size_t)kt * 512 + ks2 * 32);
                accd = __builtin_amdgcn_mfma_f32_16x16x32_bf16(a, bc, accd, 0, 0, 0);
            }
        }
        if (kt < 3) {
            #pragma unroll
            for (int q = 0; q < 4; ++q) {
                ushort4 w;
                w.x = f2bf(nf[q].x); w.y = f2bf(nf[q].y);
                w.z = f2bf(nf[q].z); w.w = f2bf(nf[q].w);
                *(ushort4*)((char*)&Xs[(kt + 1) & 1][0] + wb[q]) = w;
            }
        }
    }

    // scatter: wave w owns cols w*16+l15; C layout row=lg*4+r, col=l15
    #pragma unroll
    for (int r = 0; r < 4; ++r)
        sproj[lg * 4 + r][wv * 16 + l15] = acc[r];
    #pragma unroll
    for (int r = 0; r < 4; ++r)
        sdig[wv][lg * 4 + r][l15] = accd[r];
    __syncthreads();

    // ---- proj: rsqrt-normalize rows, write bf16 phat ----
    {
        const int row = tid >> 5;            // 0..15, 32 threads per row
        const int cq  = (tid & 31) * 4;
        fv4 p = *(const fv4*)&sproj[row][cq];
        float ssq = p[0]*p[0] + p[1]*p[1] + p[2]*p[2] + p[3]*p[3];
        #pragma unroll
        for (int m = 16; m >= 1; m >>= 1) ssq += __shfl_xor(ssq, m, 32);
        float rn = rsqrtf(ssq);
        ushort4 pk;
        pk.x = f2bf(p[0] * rn); pk.y = f2bf(p[1] * rn);
        pk.z = f2bf(p[2] * rn); pk.w = f2bf(p[3] * rn);
        *(ushort4*)&phat[(size_t)(R0 + row) * PDIM + cq] = pk;
    }

    // ---- digits: sum 8 partial K-slabs, CE via 16-lane shuffles ----
    if (tid < 256) {
        const int drow2 = tid >> 4;          // 0..15
        const int dc    = tid & 15;          // cols 10..15 zero-pad
        float d = 0.0f;
        #pragma unroll
        for (int w = 0; w < 8; ++w) d += sdig[w][drow2][dc];
        float dv = (dc < CDIM) ? d : -1e30f;
        float mx = dv;
        #pragma unroll
        for (int m = 8; m >= 1; m >>= 1) mx = fmaxf(mx, __shfl_xor(mx, m, 64));
        float e = (dc < CDIM) ? __expf(d - mx) : 0.0f;
        float s = e;
        #pragma unroll
        for (int m = 8; m >= 1; m >>= 1) s += __shfl_xor(s, m, 64);
        const int rowg = R0 + drow2;
        const int idx  = rowg & (BDIM - 1);
        const int label = (*flag_p) ? y[2 * idx] : y[idx];
        float dl = (dc == label) ? d : 0.0f;
        #pragma unroll
        for (int m = 8; m >= 1; m >>= 1) dl += __shfl_xor(dl, m, 64);
        if (dc == 0) sce[drow2] = (mx + __logf(s)) - dl;
    }
    __syncthreads();
    if (tid == 0) {
        float t = 0.0f;
        #pragma unroll
        for (int r = 0; r < 16; ++r) t += sce[r];
        atomicAdd(sup_acc, t * (1.0f / BDIM));
    }
}

// ---------------- k3: Gram row-sum via bf16 MFMA (upper-triangle tiles) ----
// LDS-staged: coalesced panel loads into swizzled A/B tiles (64 KB union),
// ds_read fragments, then reuse the A region for srow/scol/spos reduction.
__global__ __launch_bounds__(256) void k3_gram_mfma(
    const __bf16* __restrict__ ph,
    float* __restrict__ rowsum, float* __restrict__ possum)
{
    __shared__ char smem[65536];   // [0,32K) A-tile, [32K,64K) B-tile; reused later
    const int tid = threadIdx.x;

    int t = blockIdx.x;
    int ti = 0;
    while (t >= 64 - ti) { t -= 64 - ti; ++ti; }
    const int tj = ti + t;
    const int I0 = ti * 128, J0 = tj * 128;
    const bool diag    = (ti == tj);
    const bool partner = (tj == ti + 32);

    // ---- stage A (rows I0..+127) and B (rows J0..+127), swizzled ----
    {
        const int sr = tid >> 1, sh = tid & 1;     // row 0..127, half 0..1
        const int sswz = (sr & 15) << 4;
        char* As = smem;
        char* Bs = smem + 32768;
        const __bf16* gA = ph + (size_t)(I0 + sr) * PDIM + sh * 64;
        const __bf16* gB = ph + (size_t)(J0 + sr) * PDIM + sh * 64;
        #pragma unroll
        for (int i = 0; i < 8; ++i) {
            *(bfv8*)(As + sr * 256 + ((sh * 128 + i * 16) ^ sswz)) = *(const bfv8*)(gA + i * 8);
            *(bfv8*)(Bs + sr * 256 + ((sh * 128 + i * 16) ^ sswz)) = *(const bfv8*)(gB + i * 8);
        }
    }
    __syncthreads();

    const int wid = tid >> 6, lane = tid & 63;
    const int wr = wid >> 1, wc = wid & 1;
    const int l15 = lane & 15, lg = lane >> 4;
    const int fswz = l15 << 4;     // (row&15)<<4 == l15<<4 for all fragment rows

    fv4 acc[4][4] = {};
    #pragma unroll
    for (int ks = 0; ks < 4; ++ks) {
        const int cb = (ks * 64 + lg * 16) ^ fswz;
        bfv8 a[4], b[4];
        #pragma unroll
        for (int m = 0; m < 4; ++m)
            a[m] = *(const bfv8*)(smem + (wr * 64 + m * 16 + l15) * 256 + cb);
        #pragma unroll
        for (int n = 0; n < 4; ++n)
            b[n] = *(const bfv8*)(smem + 32768 + (wc * 64 + n * 16 + l15) * 256 + cb);
        #pragma unroll
        for (int m = 0; m < 4; ++m)
            #pragma unroll
            for (int n = 0; n < 4; ++n)
                acc[m][n] = __builtin_amdgcn_mfma_f32_16x16x32_bf16(a[m], b[n], acc[m][n], 0, 0, 0);
    }
    __syncthreads();               // all ds_reads consumed; safe to reuse smem

    float* srow = (float*)smem;              // [128][37]  18944 B
    float* scol = (float*)(smem + 19456);    // [128][9]    4608 B
    float* spos = (float*)(smem + 24064);    // [128]        512 B
    if (tid < 128) spos[tid] = 0.0f;
    __syncthreads();

    // epilogue: exp, diag-mask, per-lane row/col partials
    float rs_l[4][4];
    float cs_l[4] = {0, 0, 0, 0};
    #pragma unroll
    for (int m = 0; m < 4; ++m)
        #pragma unroll
        for (int r = 0; r < 4; ++r) rs_l[m][r] = 0.0f;

    #pragma unroll
    for (int m = 0; m < 4; ++m) {
        const int ribase = wr * 64 + m * 16 + lg * 4;
        #pragma unroll
        for (int n = 0; n < 4; ++n) {
            const int cj = wc * 64 + n * 16 + l15;
            #pragma unroll
            for (int r = 0; r < 4; ++r) {
                const int ri = ribase + r;
                float e = exp2f(acc[m][n][r] * EXP_SCALE);
                if (diag && ri == cj) e = 0.0f;
                rs_l[m][r] += e;
                cs_l[n] += e;
                if (partner && ri == cj) atomicAdd(&spos[ri], e);
            }
        }
    }

    // scatter partials (each slot written by exactly one lane)
    #pragma unroll
    for (int m = 0; m < 4; ++m)
        #pragma unroll
        for (int r = 0; r < 4; ++r)
            srow[(wr * 64 + m * 16 + lg * 4 + r) * 37 + wc * 16 + l15] = rs_l[m][r];
    #pragma unroll
    for (int n = 0; n < 4; ++n)
        scol[(wc * 64 + n * 16 + l15) * 9 + wr * 4 + lg] = cs_l[n];
    __syncthreads();

    // gather + one global atomic per row/col
    if (tid < 128) {
        float s = 0.0f;
        #pragma unroll
        for (int q = 0; q < 32; ++q) s += srow[tid * 37 + q];
        atomicAdd(&rowsum[I0 + tid], s);
        if (partner) atomicAdd(&possum[I0 + tid], spos[tid]);
    } else if (!diag) {
        const int col = tid - 128;
        float s = 0.0f;
        #pragma unroll
        for (int q = 0; q < 8; ++q) s += scol[col * 9 + q];
        atomicAdd(&rowsum[J0 + col], s);
        if (partner) atomicAdd(&possum[J0 + col], spos[col]);
    }
}

// ---------------- k4: final reduction (16 blocks) ----------------
__global__ __launch_bounds__(256) void k4_final(
    const float* __restrict__ rowsum, const float* __restrict__ possum,
    const float* __restrict__ sup_acc, float* __restrict__ out)
{
    __shared__ float red[4];
    const int tid = threadIdx.x;
    const int gid = blockIdx.x * 256 + tid;
    float s = 0.0f;
    #pragma unroll
    for (int i = 0; i < 2; ++i) {
        int r = gid * 2 + i;
        s += -__logf(possum[r] / rowsum[r] + EPS);
    }
    #pragma unroll
    for (int m = 32; m >= 1; m >>= 1) s += __shfl_xor(s, m, 64);
    if ((tid & 63) == 0) red[tid >> 6] = s;
    __syncthreads();
    if (tid == 0) {
        float part = (red[0] + red[1] + red[2] + red[3]) * (1.0f / TB);
        if (blockIdx.x == 0) part += LAMBDA * sup_acc[0];
        atomicAdd(out, part);
    }
}

extern "C" void kernel_launch(void* const* d_in, const int* in_sizes, int n_in,
                              void* d_out, int out_size, void* d_ws, size_t ws_size,
                              hipStream_t stream) {
    const float* xi = (const float*)d_in[1];
    const float* xj = (const float*)d_in[2];
    const int*   y  = (const int*)d_in[3];
    const float* Wp = (const float*)d_in[4];
    const float* Wc = (const float*)d_in[5];
    float* out  = (float*)d_out;

    float* ws_f   = (float*)d_ws;
    float* sup    = ws_f;
    int*   flag   = (int*)(ws_f + 1);
    float* rowsum = ws_f + 16;
    float* possum = ws_f + 16 + TB;
    unsigned short* phat_u = (unsigned short*)(ws_f + 16 + 2 * TB);
    unsigned short* WpT_u  = (unsigned short*)(ws_f + 540688);
    unsigned short* WcT_u  = (unsigned short*)(ws_f + 671760);

    k0_zero<<<(16 + 2 * TB + 255) / 256, 256, 0, stream>>>(ws_f, out);
    kf_flag<<<1, 256, 0, stream>>>(y, flag);
    kw_prep<<<(PDIM * DDIM + 16 * DDIM) / 256, 256, 0, stream>>>(Wp, Wc, WpT_u, WcT_u);
    k13_fused<<<512, 512, 0, stream>>>(xi, xj, (const __bf16*)WpT_u, (const __bf16*)WcT_u,
                                       y, flag, phat_u, sup);
    k3_gram_mfma<<<2080, 256, 0, stream>>>((const __bf16*)phat_u, rowsum, possum);
    k4_final<<<16, 256, 0, stream>>>(rowsum, possum, sup, out);
}

// Round 10
// 95.406 us; speedup vs baseline: 1.0267x; 1.0267x over previous
//
#include <hip/hip_runtime.h>
#include <hip/hip_bf16.h>
#include <math.h>

#define BDIM 4096
#define DDIM 2048
#define PDIM 128
#define CDIM 10
#define TB   8192   // 2*B

// exp(cos/TEMP) with TEMP=0.5  ->  exp2(cos * 2/ln2)
#define EXP_SCALE 2.8853900817779268f
#define LAMBDA 0.2f
#define EPS 1e-8f

typedef __bf16 bfv8 __attribute__((ext_vector_type(8)));
typedef float  fv4  __attribute__((ext_vector_type(4)));
typedef unsigned short usv8 __attribute__((ext_vector_type(8)));

typedef const __attribute__((address_space(1))) void gvoid_t;
typedef __attribute__((address_space(3))) void lvoid_t;

__device__ __forceinline__ unsigned short f2bf(float f) {
    unsigned int u = __float_as_uint(f);
    u += 0x7FFFu + ((u >> 16) & 1u);      // round-to-nearest-even
    return (unsigned short)(u >> 16);
}

// ws layout (float index):
//  [0]                    sup_acc
//  [1]                    flag (int)
//  [16 .. 16+8192)        rowsum
//  [16+8192 .. 16+16384)  possum
//  [16400 ..)             phat  [8192][128] bf16   (524288 floats)
//  [540688 ..)            WpT   [128][2048] bf16   (131072 floats)
//  [671760 ..)            WcT   [16][2048]  bf16   (16384 floats)

// ---------------- k0: zero accumulators (+ out) ----------------
__global__ void k0_zero(float* __restrict__ ws_f, float* __restrict__ out) {
    int idx = blockIdx.x * 256 + threadIdx.x;
    if (idx < 16 + 2 * TB) ws_f[idx] = 0.0f;
    if (idx == 0) out[0] = 0.0f;
}

// ---------------- kf: detect int64 label layout ----------------
__global__ void kf_flag(const int* __restrict__ y32, int* __restrict__ flag_out) {
    __shared__ int s_ok;
    if (threadIdx.x == 0) s_ok = 1;
    __syncthreads();
    int ok = 1;
    #pragma unroll
    for (int i = 0; i < 8; ++i) {
        int w = 2 * (threadIdx.x + 256 * i) + 1;   // odd words 1..4095
        if (y32[w] != 0) ok = 0;
    }
    if (!ok) atomicAnd(&s_ok, 0);
    __syncthreads();
    if (threadIdx.x == 0) *flag_out = s_ok;
}

// ---------------- kw: build bf16 transposed weights ----------------
__global__ __launch_bounds__(256) void kw_prep(
    const float* __restrict__ Wp, const float* __restrict__ Wc,
    unsigned short* __restrict__ WpT, unsigned short* __restrict__ WcT)
{
    int idx = blockIdx.x * 256 + threadIdx.x;
    if (idx < PDIM * DDIM) {
        int p = idx >> 11, k = idx & 2047;
        WpT[idx] = f2bf(Wp[(size_t)k * PDIM + p]);
    } else {
        int j = idx - PDIM * DDIM;          // < 16*2048
        int c = j >> 11, k = j & 2047;
        WcT[j] = (c < CDIM) ? f2bf(Wc[(size_t)k * CDIM + c]) : (unsigned short)0;
    }
}

// ---------------- k13: fused proj-GEMM + normalize + digits + CE -----------
// 256 blocks x 512 thr (8 waves), 1 block/CU. Block owns 32 rows; x staged
// fp32 via global_load_lds (width 16, no VGPR round-trip) into double-buffered
// swizzled LDS (BK=256 fp32, 32 KB/buf). Rule #21: linear LDS dest +
// pre-swizzled GLOBAL source (lane*16 ^ (row&15)<<4) + same XOR on ds_read.
// Waves 2x4: wr=16-row half, wc=32-col group. All 16 B-frags of a tile are
// loaded into named register arrays BEFORE the MFMA sweep (ILP);
// __launch_bounds__(512,2) gives the allocator room. Digits: wave-uniform
// compile-time rotation s==wc / s==wc+4. fp32->bf16 at fragment-read time.
__global__ __launch_bounds__(512, 2) void k13_fused(
    const float* __restrict__ xi, const float* __restrict__ xj,
    const __bf16* __restrict__ WpT, const __bf16* __restrict__ WcT,
    const int* __restrict__ y, const int* __restrict__ flag_p,
    unsigned short* __restrict__ phat, float* __restrict__ sup_acc)
{
    __shared__ float Xs[2][32][256];            // 64 KB fp32, swizzled
    __shared__ float sproj[32][132];            // 16.9 KB
    __shared__ float sdig[2][4][16][16];        // 8 KB
    __shared__ float sce[32];

    const int tid = threadIdx.x;
    const int wv = tid >> 6, lane = tid & 63;
    const int l15 = lane & 15, lg = lane >> 4;
    const int wr = wv >> 2, wc = wv & 3;
    const int R0 = blockIdx.x * 32;
    const float* src = (R0 < BDIM) ? (xi + (size_t)R0 * DDIM)
                                   : (xj + (size_t)(R0 - BDIM) * DDIM);
    const int swzr = l15 << 4;                  // a-frag read swizzle

    const __bf16* bp0 = WpT + (size_t)(wc * 32 + l15) * DDIM + lg * 8;
    const __bf16* bp1 = bp0 + (size_t)16 * DDIM;
    const __bf16* cp  = WcT + (size_t)l15 * DDIM + lg * 8;

    fv4 acc0 = {}, acc1 = {}, accd = {};

    // wave wv stages rows wv*4..wv*4+3; lane l covers ((l*16)^swz(r)) of the
    // 1 KB row-segment -> LDS gets the swizzled layout with a LINEAR dest.
    #define STAGE(KT, BUF)                                                     \
        {                                                                      \
            _Pragma("unroll")                                                  \
            for (int q = 0; q < 4; ++q) {                                      \
                const int r_ = wv * 4 + q;                                     \
                const char* g_ = (const char*)src + (size_t)r_ * (DDIM * 4)    \
                               + (KT) * 1024 + ((lane * 16) ^ ((r_ & 15) << 4)); \
                __builtin_amdgcn_global_load_lds((gvoid_t*)g_,                 \
                    (lvoid_t*)&Xs[BUF][r_][0], 16, 0, 0);                      \
            }                                                                  \
        }

    STAGE(0, 0)

    for (int kt = 0; kt < 8; ++kt) {
        __syncthreads();              // drains vmcnt: tile kt fully staged
        if (kt < 7) STAGE(kt + 1, (kt + 1) & 1)

        const char* xb = (const char*)&Xs[kt & 1][0][0] + (wr * 16 + l15) * 1024;
        const __bf16* bk0 = bp0 + kt * 256;
        const __bf16* bk1 = bp1 + kt * 256;
        const __bf16* ck  = cp  + kt * 256;

        // all B-frags of this tile up front: 16+2 loads in flight
        bfv8 b0[8], b1[8];
        #pragma unroll
        for (int s = 0; s < 8; ++s) {
            b0[s] = *(const bfv8*)(bk0 + s * 32);
            b1[s] = *(const bfv8*)(bk1 + s * 32);
        }
        bfv8 bd0 = *(const bfv8*)(ck + wc * 32);
        bfv8 bd1 = *(const bfv8*)(ck + (wc + 4) * 32);

        #pragma unroll
        for (int s = 0; s < 8; ++s) {
            fv4 x0 = *(const fv4*)(xb + ((s * 128 + lg * 32) ^ swzr));
            fv4 x1 = *(const fv4*)(xb + ((s * 128 + lg * 32 + 16) ^ swzr));
            usv8 au;
            au[0] = f2bf(x0[0]); au[1] = f2bf(x0[1]);
            au[2] = f2bf(x0[2]); au[3] = f2bf(x0[3]);
            au[4] = f2bf(x1[0]); au[5] = f2bf(x1[1]);
            au[6] = f2bf(x1[2]); au[7] = f2bf(x1[3]);
            bfv8 a = __builtin_bit_cast(bfv8, au);
            acc0 = __builtin_amdgcn_mfma_f32_16x16x32_bf16(a, b0[s], acc0, 0, 0, 0);
            acc1 = __builtin_amdgcn_mfma_f32_16x16x32_bf16(a, b1[s], acc1, 0, 0, 0);
            if (s == wc)
                accd = __builtin_amdgcn_mfma_f32_16x16x32_bf16(a, bd0, accd, 0, 0, 0);
            if (s == wc + 4)
                accd = __builtin_amdgcn_mfma_f32_16x16x32_bf16(a, bd1, accd, 0, 0, 0);
        }
    }
    #undef STAGE

    // scatter: C layout row=lg*4+r, col=l15
    #pragma unroll
    for (int r = 0; r < 4; ++r) {
        sproj[wr * 16 + lg * 4 + r][wc * 32 + l15]      = acc0[r];
        sproj[wr * 16 + lg * 4 + r][wc * 32 + 16 + l15] = acc1[r];
    }
    #pragma unroll
    for (int r = 0; r < 4; ++r)
        sdig[wr][wc][lg * 4 + r][l15] = accd[r];
    __syncthreads();

    // ---- proj: rsqrt-normalize rows, write bf16 phat ----
    {
        const int row = tid >> 4;            // 0..31, 16 threads per row
        const int c8  = (tid & 15) * 8;
        fv4 p0 = *(const fv4*)&sproj[row][c8];
        fv4 p1 = *(const fv4*)&sproj[row][c8 + 4];
        float ssq = p0[0]*p0[0] + p0[1]*p0[1] + p0[2]*p0[2] + p0[3]*p0[3]
                  + p1[0]*p1[0] + p1[1]*p1[1] + p1[2]*p1[2] + p1[3]*p1[3];
        #pragma unroll
        for (int m = 8; m >= 1; m >>= 1) ssq += __shfl_xor(ssq, m, 64);
        float rn = rsqrtf(ssq);
        usv8 pk;
        pk[0] = f2bf(p0[0]*rn); pk[1] = f2bf(p0[1]*rn);
        pk[2] = f2bf(p0[2]*rn); pk[3] = f2bf(p0[3]*rn);
        pk[4] = f2bf(p1[0]*rn); pk[5] = f2bf(p1[1]*rn);
        pk[6] = f2bf(p1[2]*rn); pk[7] = f2bf(p1[3]*rn);
        *(usv8*)&phat[(size_t)(R0 + row) * PDIM + c8] = pk;
    }

    // ---- digits: sum 4 wc-slabs per half, CE via 16-lane shuffles ----
    {
        const int drow = tid >> 4;           // 0..31
        const int dc   = tid & 15;           // cols 10..15 zero-pad
        float d = 0.0f;
        #pragma unroll
        for (int q = 0; q < 4; ++q) d += sdig[drow >> 4][q][drow & 15][dc];
        float dv = (dc < CDIM) ? d : -1e30f;
        float mx = dv;
        #pragma unroll
        for (int m = 8; m >= 1; m >>= 1) mx = fmaxf(mx, __shfl_xor(mx, m, 64));
        float e = (dc < CDIM) ? __expf(d - mx) : 0.0f;
        float s = e;
        #pragma unroll
        for (int m = 8; m >= 1; m >>= 1) s += __shfl_xor(s, m, 64);
        const int rowg = R0 + drow;
        const int idx  = rowg & (BDIM - 1);
        const int label = (*flag_p) ? y[2 * idx] : y[idx];
        float dl = (dc == label) ? d : 0.0f;
        #pragma unroll
        for (int m = 8; m >= 1; m >>= 1) dl += __shfl_xor(dl, m, 64);
        if (dc == 0) sce[drow] = (mx + __logf(s)) - dl;
    }
    __syncthreads();
    if (tid == 0) {
        float t = 0.0f;
        #pragma unroll
        for (int r = 0; r < 32; ++r) t += sce[r];
        atomicAdd(sup_acc, t * (1.0f / BDIM));
    }
}

// ---------------- k3: Gram row-sum via bf16 MFMA (upper-triangle tiles) ----
// (unchanged this round for clean attribution)
__global__ __launch_bounds__(256) void k3_gram_mfma(
    const __bf16* __restrict__ ph,
    float* __restrict__ rowsum, float* __restrict__ possum)
{
    __shared__ char smem[65536];   // [0,32K) A-tile, [32K,64K) B-tile; reused later
    const int tid = threadIdx.x;

    int t = blockIdx.x;
    int ti = 0;
    while (t >= 64 - ti) { t -= 64 - ti; ++ti; }
    const int tj = ti + t;
    const int I0 = ti * 128, J0 = tj * 128;
    const bool diag    = (ti == tj);
    const bool partner = (tj == ti + 32);

    {
        const int sr = tid >> 1, sh = tid & 1;     // row 0..127, half 0..1
        const int sswz = (sr & 15) << 4;
        char* As = smem;
        char* Bs = smem + 32768;
        const __bf16* gA = ph + (size_t)(I0 + sr) * PDIM + sh * 64;
        const __bf16* gB = ph + (size_t)(J0 + sr) * PDIM + sh * 64;
        #pragma unroll
        for (int i = 0; i < 8; ++i) {
            *(bfv8*)(As + sr * 256 + ((sh * 128 + i * 16) ^ sswz)) = *(const bfv8*)(gA + i * 8);
            *(bfv8*)(Bs + sr * 256 + ((sh * 128 + i * 16) ^ sswz)) = *(const bfv8*)(gB + i * 8);
        }
    }
    __syncthreads();

    const int wid = tid >> 6, lane = tid & 63;
    const int wr = wid >> 1, wc = wid & 1;
    const int l15 = lane & 15, lg = lane >> 4;
    const int fswz = l15 << 4;

    fv4 acc[4][4] = {};
    #pragma unroll
    for (int ks = 0; ks < 4; ++ks) {
        const int cb = (ks * 64 + lg * 16) ^ fswz;
        bfv8 a[4], b[4];
        #pragma unroll
        for (int m = 0; m < 4; ++m)
            a[m] = *(const bfv8*)(smem + (wr * 64 + m * 16 + l15) * 256 + cb);
        #pragma unroll
        for (int n = 0; n < 4; ++n)
            b[n] = *(const bfv8*)(smem + 32768 + (wc * 64 + n * 16 + l15) * 256 + cb);
        #pragma unroll
        for (int m = 0; m < 4; ++m)
            #pragma unroll
            for (int n = 0; n < 4; ++n)
                acc[m][n] = __builtin_amdgcn_mfma_f32_16x16x32_bf16(a[m], b[n], acc[m][n], 0, 0, 0);
    }
    __syncthreads();               // all ds_reads consumed; safe to reuse smem

    float* srow = (float*)smem;              // [128][37]  18944 B
    float* scol = (float*)(smem + 19456);    // [128][9]    4608 B
    float* spos = (float*)(smem + 24064);    // [128]        512 B
    if (tid < 128) spos[tid] = 0.0f;
    __syncthreads();

    float rs_l[4][4];
    float cs_l[4] = {0, 0, 0, 0};
    #pragma unroll
    for (int m = 0; m < 4; ++m)
        #pragma unroll
        for (int r = 0; r < 4; ++r) rs_l[m][r] = 0.0f;

    #pragma unroll
    for (int m = 0; m < 4; ++m) {
        const int ribase = wr * 64 + m * 16 + lg * 4;
        #pragma unroll
        for (int n = 0; n < 4; ++n) {
            const int cj = wc * 64 + n * 16 + l15;
            #pragma unroll
            for (int r = 0; r < 4; ++r) {
                const int ri = ribase + r;
                float e = exp2f(acc[m][n][r] * EXP_SCALE);
                if (diag && ri == cj) e = 0.0f;
                rs_l[m][r] += e;
                cs_l[n] += e;
                if (partner && ri == cj) atomicAdd(&spos[ri], e);
            }
        }
    }

    #pragma unroll
    for (int m = 0; m < 4; ++m)
        #pragma unroll
        for (int r = 0; r < 4; ++r)
            srow[(wr * 64 + m * 16 + lg * 4 + r) * 37 + wc * 16 + l15] = rs_l[m][r];
    #pragma unroll
    for (int n = 0; n < 4; ++n)
        scol[(wc * 64 + n * 16 + l15) * 9 + wr * 4 + lg] = cs_l[n];
    __syncthreads();

    if (tid < 128) {
        float s = 0.0f;
        #pragma unroll
        for (int q = 0; q < 32; ++q) s += srow[tid * 37 + q];
        atomicAdd(&rowsum[I0 + tid], s);
        if (partner) atomicAdd(&possum[I0 + tid], spos[tid]);
    } else if (!diag) {
        const int col = tid - 128;
        float s = 0.0f;
        #pragma unroll
        for (int q = 0; q < 8; ++q) s += scol[col * 9 + q];
        atomicAdd(&rowsum[J0 + col], s);
        if (partner) atomicAdd(&possum[J0 + col], spos[col]);
    }
}

// ---------------- k4: final reduction (16 blocks) ----------------
__global__ __launch_bounds__(256) void k4_final(
    const float* __restrict__ rowsum, const float* __restrict__ possum,
    const float* __restrict__ sup_acc, float* __restrict__ out)
{
    __shared__ float red[4];
    const int tid = threadIdx.x;
    const int gid = blockIdx.x * 256 + tid;
    float s = 0.0f;
    #pragma unroll
    for (int i = 0; i < 2; ++i) {
        int r = gid * 2 + i;
        s += -__logf(possum[r] / rowsum[r] + EPS);
    }
    #pragma unroll
    for (int m = 32; m >= 1; m >>= 1) s += __shfl_xor(s, m, 64);
    if ((tid & 63) == 0) red[tid >> 6] = s;
    __syncthreads();
    if (tid == 0) {
        float part = (red[0] + red[1] + red[2] + red[3]) * (1.0f / TB);
        if (blockIdx.x == 0) part += LAMBDA * sup_acc[0];
        atomicAdd(out, part);
    }
}

extern "C" void kernel_launch(void* const* d_in, const int* in_sizes, int n_in,
                              void* d_out, int out_size, void* d_ws, size_t ws_size,
                              hipStream_t stream) {
    const float* xi = (const float*)d_in[1];
    const float* xj = (const float*)d_in[2];
    const int*   y  = (const int*)d_in[3];
    const float* Wp = (const float*)d_in[4];
    const float* Wc = (const float*)d_in[5];
    float* out  = (float*)d_out;

    float* ws_f   = (float*)d_ws;
    float* sup    = ws_f;
    int*   flag   = (int*)(ws_f + 1);
    float* rowsum = ws_f + 16;
    float* possum = ws_f + 16 + TB;
    unsigned short* phat_u = (unsigned short*)(ws_f + 16 + 2 * TB);
    unsigned short* WpT_u  = (unsigned short*)(ws_f + 540688);
    unsigned short* WcT_u  = (unsigned short*)(ws_f + 671760);

    k0_zero<<<(16 + 2 * TB + 255) / 256, 256, 0, stream>>>(ws_f, out);
    kf_flag<<<1, 256, 0, stream>>>(y, flag);
    kw_prep<<<(PDIM * DDIM + 16 * DDIM) / 256, 256, 0, stream>>>(Wp, Wc, WpT_u, WcT_u);
    k13_fused<<<256, 512, 0, stream>>>(xi, xj, (const __bf16*)WpT_u, (const __bf16*)WcT_u,
                                       y, flag, phat_u, sup);
    k3_gram_mfma<<<2080, 256, 0, stream>>>((const __bf16*)phat_u, rowsum, possum);
    k4_final<<<16, 256, 0, stream>>>(rowsum, possum, sup, out);
}

// Round 11
// 72.679 us; speedup vs baseline: 1.3477x; 1.3127x over previous
//
#include <hip/hip_runtime.h>
#include <hip/hip_bf16.h>
#include <math.h>

#define BDIM 4096
#define DDIM 2048
#define PDIM 128
#define CDIM 10
#define TB   8192   // 2*B

// exp(cos/TEMP) with TEMP=0.5  ->  exp2(cos * 2/ln2)
#define EXP_SCALE 2.8853900817779268f
#define LAMBDA 0.2f
#define EPS 1e-8f

typedef __bf16 bfv8 __attribute__((ext_vector_type(8)));
typedef float  fv4  __attribute__((ext_vector_type(4)));
typedef unsigned short usv8 __attribute__((ext_vector_type(8)));

typedef const __attribute__((address_space(1))) void gvoid_t;
typedef __attribute__((address_space(3))) void lvoid_t;

__device__ __forceinline__ unsigned short f2bf(float f) {
    unsigned int u = __float_as_uint(f);
    u += 0x7FFFu + ((u >> 16) & 1u);      // round-to-nearest-even
    return (unsigned short)(u >> 16);
}

// Fragment order: a 16x32 bf16 MFMA operand tile (16 rows x 32 k) is stored
// as 64 lanes x 8 elems contiguous (1 KB): lane l (l15=l&15,lg=l>>4), elem j
// holds M[row l15][k lg*8+j]. Every fragment load/store = ONE coalesced 1 KB
// vector op. Layout change only -- each lane gets byte-identical data.
//
// ws layout (float index):
//  [0]                    sup_acc
//  [1]                    flag (int)
//  [16 .. 16+8192)        rowsum
//  [16+8192 .. 16+16384)  possum
//  [16400 ..)             phat_f: 512 grp x 4 ks x 512 bf16 (2 MB, frag order)
//  [540688 ..)            WpTf: 8 n x 64 ks2 x 512 bf16 (512 KB, frag order)
//  [671760 ..)            WcTf: 64 ks2 x 512 bf16 (64 KB, frag order)

// ---------------- k0: zero accumulators (+ out) ----------------
__global__ void k0_zero(float* __restrict__ ws_f, float* __restrict__ out) {
    int idx = blockIdx.x * 256 + threadIdx.x;
    if (idx < 16 + 2 * TB) ws_f[idx] = 0.0f;
    if (idx == 0) out[0] = 0.0f;
}

// ---------------- kf: detect int64 label layout ----------------
__global__ void kf_flag(const int* __restrict__ y32, int* __restrict__ flag_out) {
    __shared__ int s_ok;
    if (threadIdx.x == 0) s_ok = 1;
    __syncthreads();
    int ok = 1;
    #pragma unroll
    for (int i = 0; i < 8; ++i) {
        int w = 2 * (threadIdx.x + 256 * i) + 1;   // odd words 1..4095
        if (y32[w] != 0) ok = 0;
    }
    if (!ok) atomicAnd(&s_ok, 0);
    __syncthreads();
    if (threadIdx.x == 0) *flag_out = s_ok;
}

// ---------------- kw: build fragment-ordered bf16 weights ----------------
// WpTf[(n*64+ks2)*512 + l*8 + j] = Wp[ks2*32+(l>>4)*8+j][n*16+(l&15)]
// WcTf[(ks2)*512 + l*8 + j]      = (l&15)<10 ? Wc[ks2*32+(l>>4)*8+j][l&15] : 0
__global__ __launch_bounds__(256) void kw_prep(
    const float* __restrict__ Wp, const float* __restrict__ Wc,
    unsigned short* __restrict__ WpTf, unsigned short* __restrict__ WcTf)
{
    int idx = blockIdx.x * 256 + threadIdx.x;   // < 36864
    if (idx < 32768) {
        const int l = idx & 63, frag = idx >> 6;
        const int n = frag >> 6, ks2 = frag & 63;
        const int l15 = l & 15, lg = l >> 4;
        usv8 o;
        #pragma unroll
        for (int j = 0; j < 8; ++j)
            o[j] = f2bf(Wp[(size_t)(ks2 * 32 + lg * 8 + j) * PDIM + n * 16 + l15]);
        *(usv8*)&WpTf[(size_t)idx * 8] = o;
    } else {
        const int i2 = idx - 32768;             // < 4096
        const int l = i2 & 63, ks2 = i2 >> 6;
        const int l15 = l & 15, lg = l >> 4;
        usv8 o;
        #pragma unroll
        for (int j = 0; j < 8; ++j)
            o[j] = (l15 < CDIM) ? f2bf(Wc[(size_t)(ks2 * 32 + lg * 8 + j) * CDIM + l15])
                                : (unsigned short)0;
        *(usv8*)&WcTf[(size_t)i2 * 8] = o;
    }
}

// ---------------- k13: fused proj-GEMM + normalize + digits + CE -----------
// 256 blocks x 512 thr (8 waves). Block owns 32 rows; x staged fp32 via
// global_load_lds into double-buffered swizzled LDS (rule #21 pattern).
// B-operands now read from FRAGMENT-ORDERED WpTf/WcTf: one coalesced 1 KB
// load each (the R4..R10 invariant bottleneck was 4KB-stride lane-scattered
// B loads). phat written in fragment order for k3.
__global__ __launch_bounds__(512, 2) void k13_fused(
    const float* __restrict__ xi, const float* __restrict__ xj,
    const __bf16* __restrict__ WpTf, const __bf16* __restrict__ WcTf,
    const int* __restrict__ y, const int* __restrict__ flag_p,
    unsigned short* __restrict__ phat_f, float* __restrict__ sup_acc)
{
    __shared__ float Xs[2][32][256];            // 64 KB fp32, swizzled
    __shared__ float sproj[32][132];            // 16.9 KB
    __shared__ float sdig[2][4][16][16];        // 8 KB
    __shared__ float sce[32];

    const int tid = threadIdx.x;
    const int wv = tid >> 6, lane = tid & 63;
    const int l15 = lane & 15, lg = lane >> 4;
    const int wr = wv >> 2, wc = wv & 3;
    const int R0 = blockIdx.x * 32;
    const float* src = (R0 < BDIM) ? (xi + (size_t)R0 * DDIM)
                                   : (xj + (size_t)(R0 - BDIM) * DDIM);
    const int swzr = l15 << 4;                  // a-frag read swizzle

    fv4 acc0 = {}, acc1 = {}, accd = {};

    #define STAGE(KT, BUF)                                                     \
        {                                                                      \
            _Pragma("unroll")                                                  \
            for (int q = 0; q < 4; ++q) {                                      \
                const int r_ = wv * 4 + q;                                     \
                const char* g_ = (const char*)src + (size_t)r_ * (DDIM * 4)    \
                               + (KT) * 1024 + ((lane * 16) ^ ((r_ & 15) << 4)); \
                __builtin_amdgcn_global_load_lds((gvoid_t*)g_,                 \
                    (lvoid_t*)&Xs[BUF][r_][0], 16, 0, 0);                      \
            }                                                                  \
        }

    STAGE(0, 0)

    for (int kt = 0; kt < 8; ++kt) {
        __syncthreads();              // drains vmcnt: tile kt fully staged
        if (kt < 7) STAGE(kt + 1, (kt + 1) & 1)

        const char* xb = (const char*)&Xs[kt & 1][0][0] + (wr * 16 + l15) * 1024;

        // fragment-ordered B: coalesced 1 KB loads, all issued up front
        bfv8 b0[8], b1[8];
        #pragma unroll
        for (int s = 0; s < 8; ++s) {
            b0[s] = *(const bfv8*)(WpTf + (size_t)(((2 * wc) * 64 + kt * 8 + s) * 512) + lane * 8);
            b1[s] = *(const bfv8*)(WpTf + (size_t)(((2 * wc + 1) * 64 + kt * 8 + s) * 512) + lane * 8);
        }
        bfv8 bd0 = *(const bfv8*)(WcTf + (size_t)((kt * 8 + wc) * 512) + lane * 8);
        bfv8 bd1 = *(const bfv8*)(WcTf + (size_t)((kt * 8 + wc + 4) * 512) + lane * 8);

        #pragma unroll
        for (int s = 0; s < 8; ++s) {
            fv4 x0 = *(const fv4*)(xb + ((s * 128 + lg * 32) ^ swzr));
            fv4 x1 = *(const fv4*)(xb + ((s * 128 + lg * 32 + 16) ^ swzr));
            usv8 au;
            au[0] = f2bf(x0[0]); au[1] = f2bf(x0[1]);
            au[2] = f2bf(x0[2]); au[3] = f2bf(x0[3]);
            au[4] = f2bf(x1[0]); au[5] = f2bf(x1[1]);
            au[6] = f2bf(x1[2]); au[7] = f2bf(x1[3]);
            bfv8 a = __builtin_bit_cast(bfv8, au);
            acc0 = __builtin_amdgcn_mfma_f32_16x16x32_bf16(a, b0[s], acc0, 0, 0, 0);
            acc1 = __builtin_amdgcn_mfma_f32_16x16x32_bf16(a, b1[s], acc1, 0, 0, 0);
            if (s == wc)
                accd = __builtin_amdgcn_mfma_f32_16x16x32_bf16(a, bd0, accd, 0, 0, 0);
            if (s == wc + 4)
                accd = __builtin_amdgcn_mfma_f32_16x16x32_bf16(a, bd1, accd, 0, 0, 0);
        }
    }
    #undef STAGE

    // scatter: C layout row=lg*4+r, col=l15
    #pragma unroll
    for (int r = 0; r < 4; ++r) {
        sproj[wr * 16 + lg * 4 + r][wc * 32 + l15]      = acc0[r];
        sproj[wr * 16 + lg * 4 + r][wc * 32 + 16 + l15] = acc1[r];
    }
    #pragma unroll
    for (int r = 0; r < 4; ++r)
        sdig[wr][wc][lg * 4 + r][l15] = accd[r];
    __syncthreads();

    // ---- proj: rsqrt-normalize rows, write bf16 phat (fragment order) ----
    {
        const int row = tid >> 4;            // 0..31, 16 threads per row
        const int c8  = (tid & 15) * 8;
        fv4 p0 = *(const fv4*)&sproj[row][c8];
        fv4 p1 = *(const fv4*)&sproj[row][c8 + 4];
        float ssq = p0[0]*p0[0] + p0[1]*p0[1] + p0[2]*p0[2] + p0[3]*p0[3]
                  + p1[0]*p1[0] + p1[1]*p1[1] + p1[2]*p1[2] + p1[3]*p1[3];
        #pragma unroll
        for (int m = 8; m >= 1; m >>= 1) ssq += __shfl_xor(ssq, m, 64);
        float rn = rsqrtf(ssq);
        usv8 pk;
        pk[0] = f2bf(p0[0]*rn); pk[1] = f2bf(p0[1]*rn);
        pk[2] = f2bf(p0[2]*rn); pk[3] = f2bf(p0[3]*rn);
        pk[4] = f2bf(p1[0]*rn); pk[5] = f2bf(p1[1]*rn);
        pk[6] = f2bf(p1[2]*rn); pk[7] = f2bf(p1[3]*rn);
        const int grow = R0 + row;
        const int g = grow >> 4, lr = grow & 15;
        const int ks = c8 >> 5, lgw = (c8 >> 3) & 3;
        *(usv8*)&phat_f[(size_t)((g * 4 + ks) * 512 + (lgw * 16 + lr) * 8)] = pk;
    }

    // ---- digits: sum 4 wc-slabs per half, CE via 16-lane shuffles ----
    {
        const int drow = tid >> 4;           // 0..31
        const int dc   = tid & 15;           // cols 10..15 zero-pad
        float d = 0.0f;
        #pragma unroll
        for (int q = 0; q < 4; ++q) d += sdig[drow >> 4][q][drow & 15][dc];
        float dv = (dc < CDIM) ? d : -1e30f;
        float mx = dv;
        #pragma unroll
        for (int m = 8; m >= 1; m >>= 1) mx = fmaxf(mx, __shfl_xor(mx, m, 64));
        float e = (dc < CDIM) ? __expf(d - mx) : 0.0f;
        float s = e;
        #pragma unroll
        for (int m = 8; m >= 1; m >>= 1) s += __shfl_xor(s, m, 64);
        const int rowg = R0 + drow;
        const int idx  = rowg & (BDIM - 1);
        const int label = (*flag_p) ? y[2 * idx] : y[idx];
        float dl = (dc == label) ? d : 0.0f;
        #pragma unroll
        for (int m = 8; m >= 1; m >>= 1) dl += __shfl_xor(dl, m, 64);
        if (dc == 0) sce[drow] = (mx + __logf(s)) - dl;
    }
    __syncthreads();
    if (tid == 0) {
        float t = 0.0f;
        #pragma unroll
        for (int r = 0; r < 32; ++r) t += sce[r];
        atomicAdd(sup_acc, t * (1.0f / BDIM));
    }
}

// ---------------- k3: Gram row-sum via bf16 MFMA (upper-triangle tiles) ----
// NO staging: A/B fragments are direct coalesced 1 KB loads from the
// fragment-ordered phat_f (2 MB, L2-resident). LDS only for the epilogue
// reduction (24 KB) -> 3 blocks/CU.
__global__ __launch_bounds__(256, 3) void k3_gram_mfma(
    const __bf16* __restrict__ pf,
    float* __restrict__ rowsum, float* __restrict__ possum)
{
    __shared__ float srow[128 * 37 + 4];   // [row][wc*16+l15], stride 37
    __shared__ float scol[128 * 9 + 4];    // [col][wr*4+lg],  stride 9
    __shared__ float spos[128];
    const int tid = threadIdx.x;

    int t = blockIdx.x;
    int ti = 0;
    while (t >= 64 - ti) { t -= 64 - ti; ++ti; }
    const int tj = ti + t;
    const int I0 = ti * 128, J0 = tj * 128;
    const bool diag    = (ti == tj);
    const bool partner = (tj == ti + 32);

    if (tid < 128) spos[tid] = 0.0f;
    __syncthreads();

    const int wid = tid >> 6, lane = tid & 63;
    const int wr = wid >> 1, wc = wid & 1;
    const int l15 = lane & 15, lg = lane >> 4;

    fv4 acc[4][4] = {};
    #pragma unroll
    for (int ks = 0; ks < 4; ++ks) {
        bfv8 a[4], b[4];
        #pragma unroll
        for (int m = 0; m < 4; ++m)
            a[m] = *(const bfv8*)(pf + (size_t)(((ti * 8 + wr * 4 + m) * 4 + ks) * 512) + lane * 8);
        #pragma unroll
        for (int n = 0; n < 4; ++n)
            b[n] = *(const bfv8*)(pf + (size_t)(((tj * 8 + wc * 4 + n) * 4 + ks) * 512) + lane * 8);
        #pragma unroll
        for (int m = 0; m < 4; ++m)
            #pragma unroll
            for (int n = 0; n < 4; ++n)
                acc[m][n] = __builtin_amdgcn_mfma_f32_16x16x32_bf16(a[m], b[n], acc[m][n], 0, 0, 0);
    }

    // epilogue: exp, diag-mask, per-lane row/col partials
    float rs_l[4][4];
    float cs_l[4] = {0, 0, 0, 0};
    #pragma unroll
    for (int m = 0; m < 4; ++m)
        #pragma unroll
        for (int r = 0; r < 4; ++r) rs_l[m][r] = 0.0f;

    #pragma unroll
    for (int m = 0; m < 4; ++m) {
        const int ribase = wr * 64 + m * 16 + lg * 4;
        #pragma unroll
        for (int n = 0; n < 4; ++n) {
            const int cj = wc * 64 + n * 16 + l15;
            #pragma unroll
            for (int r = 0; r < 4; ++r) {
                const int ri = ribase + r;
                float e = exp2f(acc[m][n][r] * EXP_SCALE);
                if (diag && ri == cj) e = 0.0f;
                rs_l[m][r] += e;
                cs_l[n] += e;
                if (partner && ri == cj) atomicAdd(&spos[ri], e);
            }
        }
    }

    // scatter partials (each slot written by exactly one lane)
    #pragma unroll
    for (int m = 0; m < 4; ++m)
        #pragma unroll
        for (int r = 0; r < 4; ++r)
            srow[(wr * 64 + m * 16 + lg * 4 + r) * 37 + wc * 16 + l15] = rs_l[m][r];
    #pragma unroll
    for (int n = 0; n < 4; ++n)
        scol[(wc * 64 + n * 16 + l15) * 9 + wr * 4 + lg] = cs_l[n];
    __syncthreads();

    // gather + one global atomic per row/col
    if (tid < 128) {
        float s = 0.0f;
        #pragma unroll
        for (int q = 0; q < 32; ++q) s += srow[tid * 37 + q];
        atomicAdd(&rowsum[I0 + tid], s);
        if (partner) atomicAdd(&possum[I0 + tid], spos[tid]);
    } else if (!diag) {
        const int col = tid - 128;
        float s = 0.0f;
        #pragma unroll
        for (int q = 0; q < 8; ++q) s += scol[col * 9 + q];
        atomicAdd(&rowsum[J0 + col], s);
        if (partner) atomicAdd(&possum[J0 + col], spos[col]);
    }
}

// ---------------- k4: final reduction (16 blocks) ----------------
__global__ __launch_bounds__(256) void k4_final(
    const float* __restrict__ rowsum, const float* __restrict__ possum,
    const float* __restrict__ sup_acc, float* __restrict__ out)
{
    __shared__ float red[4];
    const int tid = threadIdx.x;
    const int gid = blockIdx.x * 256 + tid;
    float s = 0.0f;
    #pragma unroll
    for (int i = 0; i < 2; ++i) {
        int r = gid * 2 + i;
        s += -__logf(possum[r] / rowsum[r] + EPS);
    }
    #pragma unroll
    for (int m = 32; m >= 1; m >>= 1) s += __shfl_xor(s, m, 64);
    if ((tid & 63) == 0) red[tid >> 6] = s;
    __syncthreads();
    if (tid == 0) {
        float part = (red[0] + red[1] + red[2] + red[3]) * (1.0f / TB);
        if (blockIdx.x == 0) part += LAMBDA * sup_acc[0];
        atomicAdd(out, part);
    }
}

extern "C" void kernel_launch(void* const* d_in, const int* in_sizes, int n_in,
                              void* d_out, int out_size, void* d_ws, size_t ws_size,
                              hipStream_t stream) {
    const float* xi = (const float*)d_in[1];
    const float* xj = (const float*)d_in[2];
    const int*   y  = (const int*)d_in[3];
    const float* Wp = (const float*)d_in[4];
    const float* Wc = (const float*)d_in[5];
    float* out  = (float*)d_out;

    float* ws_f   = (float*)d_ws;
    float* sup    = ws_f;
    int*   flag   = (int*)(ws_f + 1);
    float* rowsum = ws_f + 16;
    float* possum = ws_f + 16 + TB;
    unsigned short* phat_u = (unsigned short*)(ws_f + 16 + 2 * TB);
    unsigned short* WpTf_u = (unsigned short*)(ws_f + 540688);
    unsigned short* WcTf_u = (unsigned short*)(ws_f + 671760);

    k0_zero<<<(16 + 2 * TB + 255) / 256, 256, 0, stream>>>(ws_f, out);
    kf_flag<<<1, 256, 0, stream>>>(y, flag);
    kw_prep<<<144, 256, 0, stream>>>(Wp, Wc, WpTf_u, WcTf_u);
    k13_fused<<<256, 512, 0, stream>>>(xi, xj, (const __bf16*)WpTf_u, (const __bf16*)WcTf_u,
                                       y, flag, phat_u, sup);
    k3_gram_mfma<<<2080, 256, 0, stream>>>((const __bf16*)phat_u, rowsum, possum);
    k4_final<<<16, 256, 0, stream>>>(rowsum, possum, sup, out);
}